// Round 1
// baseline (509.514 us; speedup 1.0000x reference)
//
#include <hip/hip_runtime.h>
#include <math.h>

#define N_CLASSES 1000
#define FEAT_DIM 1024
#define PROJ_DIM 256
#define BATCH 32
#define NUM_SUPPORT 8192

// ---------------------------------------------------------------------------
// Kernel 1: xq = x @ W   (32 x 1024) @ (1024 x 256) -> (32 x 256)
// One block per batch row, one thread per output column.
// ---------------------------------------------------------------------------
__global__ __launch_bounds__(PROJ_DIM) void proj_x_kernel(
    const float* __restrict__ x, const float* __restrict__ W,
    float* __restrict__ xq) {
  const int b = blockIdx.x;
  const int p = threadIdx.x;
  const float* __restrict__ xr = x + (size_t)b * FEAT_DIM;
  float acc = 0.0f;
#pragma unroll 8
  for (int k = 0; k < FEAT_DIM; k++) {
    acc = fmaf(xr[k], W[(size_t)k * PROJ_DIM + p], acc);
  }
  xq[(size_t)b * PROJ_DIM + p] = acc;
}

// ---------------------------------------------------------------------------
// Kernel 2: sxp = sx @ W   (8192 x 1024) @ (1024 x 256) -> (8192 x 256)
// Tiled fp32 GEMM: 64x64 block tile, 4x4 per-thread microtile, BK=16.
// ---------------------------------------------------------------------------
#define BM 64
#define BN 64
#define BK 16

__global__ __launch_bounds__(256) void sxp_gemm_kernel(
    const float* __restrict__ sx, const float* __restrict__ W,
    float* __restrict__ sxp) {
  __shared__ float As[BK][BM + 1];  // As[k][m]
  __shared__ float Bs[BK][BN + 1];  // Bs[k][n]

  const int tid = threadIdx.x;
  const int bm = blockIdx.x * BM;
  const int bn = blockIdx.y * BN;
  const int tr = tid >> 4;  // 0..15
  const int tc = tid & 15;  // 0..15

  float acc[4][4] = {};

  for (int kt = 0; kt < FEAT_DIM; kt += BK) {
    // Load A tile (64 rows x 16 k) transposed into As[k][m]
#pragma unroll
    for (int i = 0; i < 4; i++) {
      const int idx = tid + i * 256;  // 0..1023
      const int r = idx >> 4;         // 0..63
      const int c = idx & 15;         // 0..15
      As[c][r] = sx[(size_t)(bm + r) * FEAT_DIM + kt + c];
    }
    // Load B tile (16 k x 64 cols)
#pragma unroll
    for (int i = 0; i < 4; i++) {
      const int idx = tid + i * 256;
      const int r = idx >> 6;  // 0..15
      const int c = idx & 63;  // 0..63
      Bs[r][c] = W[(size_t)(kt + r) * PROJ_DIM + bn + c];
    }
    __syncthreads();

#pragma unroll
    for (int k = 0; k < BK; k++) {
      float a[4], bb[4];
#pragma unroll
      for (int i = 0; i < 4; i++) a[i] = As[k][tr * 4 + i];
#pragma unroll
      for (int j = 0; j < 4; j++) bb[j] = Bs[k][tc * 4 + j];
#pragma unroll
      for (int i = 0; i < 4; i++)
#pragma unroll
        for (int j = 0; j < 4; j++) acc[i][j] = fmaf(a[i], bb[j], acc[i][j]);
    }
    __syncthreads();
  }

#pragma unroll
  for (int i = 0; i < 4; i++)
#pragma unroll
    for (int j = 0; j < 4; j++)
      sxp[(size_t)(bm + tr * 4 + i) * PROJ_DIM + bn + tc * 4 + j] = acc[i][j];
}

// ---------------------------------------------------------------------------
// Kernel 3: per batch row: scores -> softmax -> class-bin accumulate -> log.
// One block (256 threads) per batch row; each thread owns 32 support rows.
// s_sq is computed on the fly in the same pass that reads sxp.
// ---------------------------------------------------------------------------
__global__ __launch_bounds__(256) void score_softmax_kernel(
    const float* __restrict__ xq, const float* __restrict__ sxp,
    const int* __restrict__ sy, float* __restrict__ out) {
  __shared__ float xql[PROJ_DIM];
  __shared__ float red[4];
  __shared__ float cls[N_CLASSES];

  const int b = blockIdx.x;
  const int t = threadIdx.x;
  const int lane = t & 63;
  const int wave = t >> 6;

  xql[t] = xq[(size_t)b * PROJ_DIM + t];
  for (int c = t; c < N_CLASSES; c += 256) cls[c] = 0.0f;
  __syncthreads();

  // x_sq = ||xq_b||^2
  float v = xql[t] * xql[t];
#pragma unroll
  for (int o = 32; o > 0; o >>= 1) v += __shfl_down(v, o, 64);
  if (lane == 0) red[wave] = v;
  __syncthreads();
  const float x_sq = red[0] + red[1] + red[2] + red[3];
  __syncthreads();  // before red is reused

  // scores for my 32 support rows
  float scores[32];
  float lmax = -1e30f;
#pragma unroll
  for (int jj = 0; jj < 32; jj++) {
    const int j = jj * 256 + t;
    const float* __restrict__ row = sxp + (size_t)j * PROJ_DIM;
    float dot = 0.0f, rsq = 0.0f;
#pragma unroll 8
    for (int p = 0; p < PROJ_DIM; p++) {
      const float rv = row[p];
      dot = fmaf(xql[p], rv, dot);
      rsq = fmaf(rv, rv, rsq);
    }
    const float sc = 2.0f * dot - rsq - x_sq;  // -(x_sq + s_sq - 2*dot)
    scores[jj] = sc;
    lmax = fmaxf(lmax, sc);
  }

  // block max
#pragma unroll
  for (int o = 32; o > 0; o >>= 1) lmax = fmaxf(lmax, __shfl_down(lmax, o, 64));
  if (lane == 0) red[wave] = lmax;
  __syncthreads();
  const float gmax = fmaxf(fmaxf(red[0], red[1]), fmaxf(red[2], red[3]));
  __syncthreads();

  // sum of exp + class accumulation
  float lsum = 0.0f;
#pragma unroll
  for (int jj = 0; jj < 32; jj++) {
    const int j = jj * 256 + t;
    const float e = expf(scores[jj] - gmax);
    lsum += e;
    atomicAdd(&cls[sy[j]], e);
  }
#pragma unroll
  for (int o = 32; o > 0; o >>= 1) lsum += __shfl_down(lsum, o, 64);
  if (lane == 0) red[wave] = lsum;
  __syncthreads();
  const float denom = red[0] + red[1] + red[2] + red[3];

  const float inv = 1.0f / denom;
  for (int c = t; c < N_CLASSES; c += 256) {
    out[(size_t)b * N_CLASSES + c] = logf(cls[c] * inv + 1e-12f);
  }
}

// ---------------------------------------------------------------------------
extern "C" void kernel_launch(void* const* d_in, const int* in_sizes, int n_in,
                              void* d_out, int out_size, void* d_ws,
                              size_t ws_size, hipStream_t stream) {
  const float* x = (const float*)d_in[0];         // (32, 1024)
  const float* sx = (const float*)d_in[1];        // (8192, 1024)
  const float* W = (const float*)d_in[2];         // (1024, 256)
  const int* sy = (const int*)d_in[3];            // (8192,)
  float* out = (float*)d_out;                     // (32, 1000)

  float* xq = (float*)d_ws;                       // 32*256 floats
  float* sxp = xq + BATCH * PROJ_DIM;             // 8192*256 floats

  proj_x_kernel<<<dim3(BATCH), dim3(PROJ_DIM), 0, stream>>>(x, W, xq);
  sxp_gemm_kernel<<<dim3(NUM_SUPPORT / BM, PROJ_DIM / BN), dim3(256), 0,
                    stream>>>(sx, W, sxp);
  score_softmax_kernel<<<dim3(BATCH), dim3(256), 0, stream>>>(xq, sxp, sy, out);
}

// Round 2
// 209.938 us; speedup vs baseline: 2.4270x; 2.4270x over previous
//
#include <hip/hip_runtime.h>
#include <math.h>

#define N_CLASSES 1000
#define FEAT_DIM 1024
#define PROJ_DIM 256
#define BATCH 32
#define NUM_SUPPORT 8192

// Monotonic float <-> unsigned encoding for atomicMax on floats.
__device__ inline unsigned enc_f(float f) {
  unsigned u = __float_as_uint(f);
  return (u & 0x80000000u) ? ~u : (u | 0x80000000u);
}
__device__ inline float dec_f(unsigned e) {
  return (e & 0x80000000u) ? __uint_as_float(e & 0x7FFFFFFFu)
                           : __uint_as_float(~e);
}

// ---------------------------------------------------------------------------
// Kernel 1: xq = x @ W (32x1024)@(1024x256) -> (32x256); also xsq[b]=||xq_b||^2
// and init rowmaxU to 0 (encoded -inf). One block per batch row.
// ---------------------------------------------------------------------------
__global__ __launch_bounds__(PROJ_DIM) void proj_x_kernel(
    const float* __restrict__ x, const float* __restrict__ W,
    float* __restrict__ xq, float* __restrict__ xsq,
    unsigned* __restrict__ rowmaxU) {
  __shared__ float red[4];
  const int b = blockIdx.x;
  const int t = threadIdx.x;
  if (b == 0 && t < BATCH) rowmaxU[t] = 0u;  // smallest encoded value

  const float* __restrict__ xr = x + (size_t)b * FEAT_DIM;
  float acc = 0.0f;
#pragma unroll 8
  for (int k = 0; k < FEAT_DIM; k++) {
    acc = fmaf(xr[k], W[(size_t)k * PROJ_DIM + t], acc);
  }
  xq[(size_t)b * PROJ_DIM + t] = acc;

  // block-reduce sum of squares
  float v = acc * acc;
  const int lane = t & 63, wave = t >> 6;
#pragma unroll
  for (int o = 32; o > 0; o >>= 1) v += __shfl_down(v, o, 64);
  if (lane == 0) red[wave] = v;
  __syncthreads();
  if (t == 0) xsq[b] = red[0] + red[1] + red[2] + red[3];
}

// ---------------------------------------------------------------------------
// Kernel 2: sxp = sx @ W (8192x1024)@(1024x256) -> (8192x256)
// 128x64 tile, BK=16, 8x4 microtile, float4 loads, register prefetch.
// ---------------------------------------------------------------------------
#define BM 128
#define BN 64
#define BK 16

__global__ __launch_bounds__(256) void sxp_gemm_kernel(
    const float* __restrict__ sx, const float* __restrict__ W,
    float* __restrict__ sxp) {
  __shared__ float As[BK][BM + 4];  // [k][m]
  __shared__ float Bs[BK][BN + 4];  // [k][n]

  const int tid = threadIdx.x;
  const int bm = blockIdx.x * BM;
  const int bn = blockIdx.y * BN;
  const int tr = tid >> 4;  // 0..15 -> rows tr*8..+7
  const int tc = tid & 15;  // 0..15 -> cols tc*4..+3

  // A-load indices: 2 float4 per thread
  const int af0 = tid;        // f4 idx 0..255
  const int af1 = tid + 256;  // 256..511
  const int ar0 = af0 >> 2, ak0 = (af0 & 3) * 4;
  const int ar1 = af1 >> 2, ak1 = (af1 & 3) * 4;
  // B-load: 1 float4 per thread
  const int br = tid >> 4, bc = (tid & 15) * 4;

  float acc[8][4] = {};
  float4 aReg0, aReg1, bReg;

  // prefetch kt = 0
  aReg0 = *(const float4*)&sx[(size_t)(bm + ar0) * FEAT_DIM + ak0];
  aReg1 = *(const float4*)&sx[(size_t)(bm + ar1) * FEAT_DIM + ak1];
  bReg = *(const float4*)&W[(size_t)br * PROJ_DIM + bn + bc];

  for (int kt = 0; kt < FEAT_DIM; kt += BK) {
    // store staged regs to LDS (A transposed)
    As[ak0 + 0][ar0] = aReg0.x;
    As[ak0 + 1][ar0] = aReg0.y;
    As[ak0 + 2][ar0] = aReg0.z;
    As[ak0 + 3][ar0] = aReg0.w;
    As[ak1 + 0][ar1] = aReg1.x;
    As[ak1 + 1][ar1] = aReg1.y;
    As[ak1 + 2][ar1] = aReg1.z;
    As[ak1 + 3][ar1] = aReg1.w;
    *(float4*)&Bs[br][bc] = bReg;
    __syncthreads();

    // prefetch next tile
    if (kt + BK < FEAT_DIM) {
      const int k2 = kt + BK;
      aReg0 = *(const float4*)&sx[(size_t)(bm + ar0) * FEAT_DIM + k2 + ak0];
      aReg1 = *(const float4*)&sx[(size_t)(bm + ar1) * FEAT_DIM + k2 + ak1];
      bReg = *(const float4*)&W[(size_t)(k2 + br) * PROJ_DIM + bn + bc];
    }

#pragma unroll
    for (int k = 0; k < BK; k++) {
      float4 a0 = *(const float4*)&As[k][tr * 8];
      float4 a1 = *(const float4*)&As[k][tr * 8 + 4];
      float4 b0 = *(const float4*)&Bs[k][tc * 4];
      const float a[8] = {a0.x, a0.y, a0.z, a0.w, a1.x, a1.y, a1.z, a1.w};
      const float bb[4] = {b0.x, b0.y, b0.z, b0.w};
#pragma unroll
      for (int i = 0; i < 8; i++)
#pragma unroll
        for (int j = 0; j < 4; j++) acc[i][j] = fmaf(a[i], bb[j], acc[i][j]);
    }
    __syncthreads();
  }

#pragma unroll
  for (int i = 0; i < 8; i++) {
    float4 o = {acc[i][0], acc[i][1], acc[i][2], acc[i][3]};
    *(float4*)&sxp[(size_t)(bm + tr * 8 + i) * PROJ_DIM + bn + tc * 4] = o;
  }
}

// ---------------------------------------------------------------------------
// Kernel 3a: scores[b][j] = 2*<xq_b, sxp_j> - ||sxp_j||^2 - ||xq_b||^2
// Grid (32 j-chunks, 8 b-groups); thread owns 1 support row x 4 batch rows.
// Also per-b block max -> global atomicMax (encoded).
// ---------------------------------------------------------------------------
__global__ __launch_bounds__(256) void score_kernel(
    const float* __restrict__ xq, const float* __restrict__ xsq,
    const float* __restrict__ sxp, float* __restrict__ sc,
    unsigned* __restrict__ rowmaxU) {
  __shared__ float xqT4[PROJ_DIM * 4];  // [p][c] for this b-group
  __shared__ float xsqL[4];
  __shared__ float redm[4][4];  // [c][wave]

  const int t = threadIdx.x;
  const int jc = blockIdx.x;  // 0..31
  const int bg = blockIdx.y;  // 0..7

  // load xq slice, transposed to [p][c]
#pragma unroll
  for (int i = 0; i < 4; i++) xqT4[t * 4 + i] = xq[(bg * 4 + i) * PROJ_DIM + t];
  if (t < 4) xsqL[t] = xsq[bg * 4 + t];
  __syncthreads();

  const int j = jc * 256 + t;
  const float4* __restrict__ row4 = (const float4*)(sxp + (size_t)j * PROJ_DIM);
  float dot[4] = {0.f, 0.f, 0.f, 0.f};
  float rsq = 0.f;

#pragma unroll 4
  for (int q = 0; q < PROJ_DIM / 4; q++) {
    const float4 rv = row4[q];
    const float xv[4] = {rv.x, rv.y, rv.z, rv.w};
#pragma unroll
    for (int c = 0; c < 4; c++) {
      const int p = q * 4 + c;
      const float4 xb = *(const float4*)&xqT4[p * 4];
      rsq = fmaf(xv[c], xv[c], rsq);
      dot[0] = fmaf(xv[c], xb.x, dot[0]);
      dot[1] = fmaf(xv[c], xb.y, dot[1]);
      dot[2] = fmaf(xv[c], xb.z, dot[2]);
      dot[3] = fmaf(xv[c], xb.w, dot[3]);
    }
  }

  float s[4];
  const int lane = t & 63, wave = t >> 6;
#pragma unroll
  for (int c = 0; c < 4; c++) {
    s[c] = 2.0f * dot[c] - rsq - xsqL[c];
    sc[(size_t)(bg * 4 + c) * NUM_SUPPORT + j] = s[c];
    float v = s[c];
#pragma unroll
    for (int o = 1; o < 64; o <<= 1) v = fmaxf(v, __shfl_xor(v, o, 64));
    if (lane == 0) redm[c][wave] = v;
  }
  __syncthreads();
  if (t < 4) {
    float m = fmaxf(fmaxf(redm[t][0], redm[t][1]),
                    fmaxf(redm[t][2], redm[t][3]));
    atomicMax(&rowmaxU[bg * 4 + t], enc_f(m));
  }
}

// ---------------------------------------------------------------------------
// Kernel 3b: per batch row: exp, class-bin accumulate, log. One block per b.
// ---------------------------------------------------------------------------
__global__ __launch_bounds__(256) void finish_kernel(
    const float* __restrict__ sc, const unsigned* __restrict__ rowmaxU,
    const int* __restrict__ sy, float* __restrict__ out) {
  __shared__ float cls[N_CLASSES];
  __shared__ float red[4];

  const int b = blockIdx.x;
  const int t = threadIdx.x;
  const int lane = t & 63, wave = t >> 6;
  const float m = dec_f(rowmaxU[b]);

  for (int c = t; c < N_CLASSES; c += 256) cls[c] = 0.0f;
  __syncthreads();

  float lsum = 0.0f;
#pragma unroll
  for (int jj = 0; jj < NUM_SUPPORT / 256; jj++) {
    const int j = jj * 256 + t;
    const float e = expf(sc[(size_t)b * NUM_SUPPORT + j] - m);
    lsum += e;
    atomicAdd(&cls[sy[j]], e);
  }
#pragma unroll
  for (int o = 32; o > 0; o >>= 1) lsum += __shfl_down(lsum, o, 64);
  if (lane == 0) red[wave] = lsum;
  __syncthreads();
  const float denom = red[0] + red[1] + red[2] + red[3];

  const float inv = 1.0f / denom;
  for (int c = t; c < N_CLASSES; c += 256) {
    out[(size_t)b * N_CLASSES + c] = logf(cls[c] * inv + 1e-12f);
  }
}

// ---------------------------------------------------------------------------
extern "C" void kernel_launch(void* const* d_in, const int* in_sizes, int n_in,
                              void* d_out, int out_size, void* d_ws,
                              size_t ws_size, hipStream_t stream) {
  const float* x = (const float*)d_in[0];   // (32, 1024)
  const float* sx = (const float*)d_in[1];  // (8192, 1024)
  const float* W = (const float*)d_in[2];   // (1024, 256)
  const int* sy = (const int*)d_in[3];      // (8192,)
  float* out = (float*)d_out;               // (32, 1000)

  float* xq = (float*)d_ws;                          // 32*256
  float* xsq = xq + BATCH * PROJ_DIM;                // 32
  unsigned* rowmaxU = (unsigned*)(xsq + BATCH);      // 32
  float* sxp = (float*)(rowmaxU + BATCH);            // 8192*256
  float* sc = sxp + (size_t)NUM_SUPPORT * PROJ_DIM;  // 32*8192

  proj_x_kernel<<<dim3(BATCH), dim3(PROJ_DIM), 0, stream>>>(x, W, xq, xsq,
                                                            rowmaxU);
  sxp_gemm_kernel<<<dim3(NUM_SUPPORT / BM, PROJ_DIM / BN), dim3(256), 0,
                    stream>>>(sx, W, sxp);
  score_kernel<<<dim3(NUM_SUPPORT / 256, BATCH / 4), dim3(256), 0, stream>>>(
      xq, xsq, sxp, sc, rowmaxU);
  finish_kernel<<<dim3(BATCH), dim3(256), 0, stream>>>(sc, rowmaxU, sy, out);
}

// Round 3
// 159.436 us; speedup vs baseline: 3.1957x; 1.3168x over previous
//
#include <hip/hip_runtime.h>
#include <hip/hip_bf16.h>
#include <math.h>

#define N_CLASSES 1000
#define FEAT_DIM 1024
#define PROJ_DIM 256
#define BATCH 32
#define NUM_SUPPORT 8192
#define KBIG 3072   // [Ah | Ah | Al] x [Wh ; Wl ; Wh]
#define ACOLS 2048  // stored A: row = [Ah(1024) | Al(1024)]

typedef __attribute__((ext_vector_type(8))) short bf16x8;
typedef __attribute__((ext_vector_type(4))) float f32x4;

__device__ inline unsigned short bf16bits(float v) {
  __hip_bfloat16 h = __float2bfloat16(v);
  return *reinterpret_cast<unsigned short*>(&h);
}
__device__ inline float bf16tof(unsigned short u) {
  __hip_bfloat16 h;
  *reinterpret_cast<unsigned short*>(&h) = u;
  return __bfloat162float(h);
}

// Monotonic float <-> unsigned encoding for atomicMax on floats.
__device__ inline unsigned enc_f(float f) {
  unsigned u = __float_as_uint(f);
  return (u & 0x80000000u) ? ~u : (u | 0x80000000u);
}
__device__ inline float dec_f(unsigned e) {
  return (e & 0x80000000u) ? __uint_as_float(e & 0x7FFFFFFFu)
                           : __uint_as_float(~e);
}

// ---------------------------------------------------------------------------
// prep_A: sx (8192x1024 f32) -> A2 (8192x2048 bf16): row = [hi(1024)|lo(1024)]
// ---------------------------------------------------------------------------
__global__ __launch_bounds__(256) void prep_a_kernel(
    const float* __restrict__ sx, unsigned short* __restrict__ A2) {
  const int idx = blockIdx.x * 256 + threadIdx.x;  // 8192*256 threads, 4 f each
  const int r = idx >> 8;
  const int q = idx & 255;
  const float4 v = *(const float4*)&sx[(size_t)r * FEAT_DIM + q * 4];
  const float vv[4] = {v.x, v.y, v.z, v.w};
  ushort4 h, l;
  unsigned short hb[4], lb[4];
#pragma unroll
  for (int i = 0; i < 4; i++) {
    hb[i] = bf16bits(vv[i]);
    lb[i] = bf16bits(vv[i] - bf16tof(hb[i]));
  }
  h.x = hb[0]; h.y = hb[1]; h.z = hb[2]; h.w = hb[3];
  l.x = lb[0]; l.y = lb[1]; l.z = lb[2]; l.w = lb[3];
  *(ushort4*)&A2[(size_t)r * ACOLS + q * 4] = h;
  *(ushort4*)&A2[(size_t)r * ACOLS + 1024 + q * 4] = l;
}

// ---------------------------------------------------------------------------
// prep_W: W (1024x256 f32, k-major) -> WT (256x3072 bf16, n-major):
// WT[n] = [Wh(k 0..1023) | Wl | Wh]
// ---------------------------------------------------------------------------
__global__ __launch_bounds__(256) void prep_w_kernel(
    const float* __restrict__ W, unsigned short* __restrict__ WT) {
  const int idx = blockIdx.x * 256 + threadIdx.x;  // 256*1024
  const int n = idx >> 10;
  const int k = idx & 1023;
  const float v = W[(size_t)k * PROJ_DIM + n];
  const unsigned short h = bf16bits(v);
  const unsigned short l = bf16bits(v - bf16tof(h));
  WT[(size_t)n * KBIG + k] = h;
  WT[(size_t)n * KBIG + 1024 + k] = l;
  WT[(size_t)n * KBIG + 2048 + k] = h;
}

// ---------------------------------------------------------------------------
// proj_x: xq = x @ W (fp32). Grid (32 b, 8 col-chunks), 256 thr = 32c x 8k.
// Also inits rowmaxU.
// ---------------------------------------------------------------------------
__global__ __launch_bounds__(256) void proj_x_kernel(
    const float* __restrict__ x, const float* __restrict__ W,
    float* __restrict__ xq, unsigned* __restrict__ rowmaxU) {
  __shared__ float part[256];
  const int b = blockIdx.x, cc = blockIdx.y;
  const int t = threadIdx.x;
  if (b == 0 && cc == 0 && t < BATCH) rowmaxU[t] = 0u;

  const int col = t & 31, ks = t >> 5;
  const int gc = cc * 32 + col;
  const int k0 = ks * 128;
  float s = 0.f;
#pragma unroll 8
  for (int k = 0; k < 128; k++) {
    s = fmaf(x[(size_t)b * FEAT_DIM + k0 + k],
             W[(size_t)(k0 + k) * PROJ_DIM + gc], s);
  }
  part[t] = s;
  __syncthreads();
  if (t < 32) {
    float acc = 0.f;
#pragma unroll
    for (int i = 0; i < 8; i++) acc += part[i * 32 + t];
    xq[(size_t)b * PROJ_DIM + cc * 32 + t] = acc;
  }
}

// ---------------------------------------------------------------------------
// sxp = A2(split bf16) @ WT^T via MFMA, K=3072. Tile 128x64, BK=64, 4 waves
// (2x2), wave tile 64x32 (4x2 frags of 16x16x32). XOR-swizzled LDS chunks;
// global_load_lds width-16 staging. Grid (64, 4) = 256 blocks.
// ---------------------------------------------------------------------------
__global__ __launch_bounds__(256) void sxp_mfma_kernel(
    const unsigned short* __restrict__ A2, const unsigned short* __restrict__ WT,
    float* __restrict__ sxp) {
  __shared__ unsigned short At[128 * 64];  // row r at shorts r*64; 8 chunks/row
  __shared__ unsigned short Bt[64 * 64];

  const int tid = threadIdx.x;
  const int w = tid >> 6;
  const int lane = tid & 63;
  const int bm = blockIdx.x * 128;
  const int bn = blockIdx.y * 64;
  const int wm = w & 1, wn = w >> 1;
  const int m16 = lane & 15, quad = lane >> 4;
  const int lrow8 = lane >> 3;          // 0..7
  const int g = (lane & 7) ^ lrow8;     // permuted global chunk index

  f32x4 acc[4][2];
#pragma unroll
  for (int mt = 0; mt < 4; mt++)
#pragma unroll
    for (int nt = 0; nt < 2; nt++) acc[mt][nt] = (f32x4){0.f, 0.f, 0.f, 0.f};

  for (int kb = 0; kb < KBIG; kb += 64) {
    const int acol = (kb < 1024) ? kb : kb - 1024;
    // stage A tile (128 x 64 bf16): 4 instrs/wave, 8 rows each
#pragma unroll
    for (int i = 0; i < 4; i++) {
      const int row = w * 32 + i * 8 + lrow8;
      const unsigned short* gp =
          A2 + (size_t)(bm + row) * ACOLS + acol + g * 8;
      __builtin_amdgcn_global_load_lds(
          (const __attribute__((address_space(1))) void*)gp,
          (__attribute__((address_space(3))) void*)(At + (w * 32 + i * 8) * 64),
          16, 0, 0);
    }
    // stage B tile (64 n x 64 k bf16): 2 instrs/wave
#pragma unroll
    for (int i = 0; i < 2; i++) {
      const int nrow = w * 16 + i * 8 + lrow8;
      const unsigned short* gp = WT + (size_t)(bn + nrow) * KBIG + kb + g * 8;
      __builtin_amdgcn_global_load_lds(
          (const __attribute__((address_space(1))) void*)gp,
          (__attribute__((address_space(3))) void*)(Bt + (w * 16 + i * 8) * 64),
          16, 0, 0);
    }
    __syncthreads();

#pragma unroll
    for (int s = 0; s < 2; s++) {
      const int slot = (s * 4 + quad) ^ (m16 & 7);
      bf16x8 af[4], bf[2];
#pragma unroll
      for (int mt = 0; mt < 4; mt++) {
        const int row = wm * 64 + mt * 16 + m16;
        af[mt] = *(bf16x8*)&At[row * 64 + slot * 8];
      }
#pragma unroll
      for (int nt = 0; nt < 2; nt++) {
        const int nrow = wn * 32 + nt * 16 + m16;
        bf[nt] = *(bf16x8*)&Bt[nrow * 64 + slot * 8];
      }
#pragma unroll
      for (int mt = 0; mt < 4; mt++)
#pragma unroll
        for (int nt = 0; nt < 2; nt++)
          acc[mt][nt] = __builtin_amdgcn_mfma_f32_16x16x32_bf16(
              af[mt], bf[nt], acc[mt][nt], 0, 0, 0);
    }
    __syncthreads();
  }

  // epilogue: C/D layout col=lane&15 (n), row=quad*4+reg (m)
#pragma unroll
  for (int mt = 0; mt < 4; mt++)
#pragma unroll
    for (int nt = 0; nt < 2; nt++)
#pragma unroll
      for (int r = 0; r < 4; r++) {
        const int mg = bm + wm * 64 + mt * 16 + quad * 4 + r;
        const int ng = bn + wn * 32 + nt * 16 + m16;
        sxp[(size_t)mg * PROJ_DIM + ng] = acc[mt][nt][r];
      }
}

// ---------------------------------------------------------------------------
// score: scores[b][j] = 2<xq_b, sxp_j> - ||sxp_j||^2 - ||xq_b||^2
// Grid (32 j-chunks, 8 b-groups of 4). x_sq computed in-block.
// ---------------------------------------------------------------------------
__global__ __launch_bounds__(256) void score_kernel(
    const float* __restrict__ xq, const float* __restrict__ sxp,
    float* __restrict__ sc, unsigned* __restrict__ rowmaxU) {
  __shared__ float xqT4[PROJ_DIM * 4];
  __shared__ float xsqL[4];
  __shared__ float redm[4][4];

  const int t = threadIdx.x;
  const int jc = blockIdx.x;
  const int bg = blockIdx.y;
  const int lane = t & 63, wave = t >> 6;

  float xv[4];
#pragma unroll
  for (int i = 0; i < 4; i++) {
    xv[i] = xq[(size_t)(bg * 4 + i) * PROJ_DIM + t];
    xqT4[t * 4 + i] = xv[i];
  }
  // x_sq reductions
#pragma unroll
  for (int i = 0; i < 4; i++) {
    float v = xv[i] * xv[i];
#pragma unroll
    for (int o = 1; o < 64; o <<= 1) v += __shfl_xor(v, o, 64);
    if (lane == 0) redm[i][wave] = v;
  }
  __syncthreads();
  if (t < 4) xsqL[t] = redm[t][0] + redm[t][1] + redm[t][2] + redm[t][3];
  __syncthreads();

  const int j = jc * 256 + t;
  const float4* __restrict__ row4 = (const float4*)(sxp + (size_t)j * PROJ_DIM);
  float dot[4] = {0.f, 0.f, 0.f, 0.f};
  float rsq = 0.f;

#pragma unroll 4
  for (int q = 0; q < PROJ_DIM / 4; q++) {
    const float4 rv = row4[q];
    const float rr[4] = {rv.x, rv.y, rv.z, rv.w};
#pragma unroll
    for (int c = 0; c < 4; c++) {
      const int p = q * 4 + c;
      const float4 xb = *(const float4*)&xqT4[p * 4];
      rsq = fmaf(rr[c], rr[c], rsq);
      dot[0] = fmaf(rr[c], xb.x, dot[0]);
      dot[1] = fmaf(rr[c], xb.y, dot[1]);
      dot[2] = fmaf(rr[c], xb.z, dot[2]);
      dot[3] = fmaf(rr[c], xb.w, dot[3]);
    }
  }

#pragma unroll
  for (int c = 0; c < 4; c++) {
    const float s = 2.0f * dot[c] - rsq - xsqL[c];
    sc[(size_t)(bg * 4 + c) * NUM_SUPPORT + j] = s;
    float v = s;
#pragma unroll
    for (int o = 1; o < 64; o <<= 1) v = fmaxf(v, __shfl_xor(v, o, 64));
    if (lane == 0) redm[c][wave] = v;
  }
  __syncthreads();
  if (t < 4) {
    const float m =
        fmaxf(fmaxf(redm[t][0], redm[t][1]), fmaxf(redm[t][2], redm[t][3]));
    atomicMax(&rowmaxU[bg * 4 + t], enc_f(m));
  }
}

// ---------------------------------------------------------------------------
// finish: exp, class bins, log. One block (1024 thr) per batch row.
// ---------------------------------------------------------------------------
__global__ __launch_bounds__(1024) void finish_kernel(
    const float* __restrict__ sc, const unsigned* __restrict__ rowmaxU,
    const int* __restrict__ sy, float* __restrict__ out) {
  __shared__ float cls[N_CLASSES];
  __shared__ float red[16];

  const int b = blockIdx.x;
  const int t = threadIdx.x;
  const int lane = t & 63, wave = t >> 6;
  const float m = dec_f(rowmaxU[b]);

  for (int c = t; c < N_CLASSES; c += 1024) cls[c] = 0.0f;
  __syncthreads();

  float lsum = 0.0f;
#pragma unroll
  for (int jj = 0; jj < NUM_SUPPORT / 1024; jj++) {
    const int j = jj * 1024 + t;
    const float e = expf(sc[(size_t)b * NUM_SUPPORT + j] - m);
    lsum += e;
    atomicAdd(&cls[sy[j]], e);
  }
#pragma unroll
  for (int o = 1; o < 64; o <<= 1) lsum += __shfl_xor(lsum, o, 64);
  if (lane == 0) red[wave] = lsum;
  __syncthreads();
  if (t == 0) {
    float s = 0.f;
#pragma unroll
    for (int i = 0; i < 16; i++) s += red[i];
    red[0] = s;
  }
  __syncthreads();
  const float inv = 1.0f / red[0];
  for (int c = t; c < N_CLASSES; c += 1024) {
    out[(size_t)b * N_CLASSES + c] = logf(cls[c] * inv + 1e-12f);
  }
}

// ---------------------------------------------------------------------------
extern "C" void kernel_launch(void* const* d_in, const int* in_sizes, int n_in,
                              void* d_out, int out_size, void* d_ws,
                              size_t ws_size, hipStream_t stream) {
  const float* x = (const float*)d_in[0];   // (32, 1024)
  const float* sx = (const float*)d_in[1];  // (8192, 1024)
  const float* W = (const float*)d_in[2];   // (1024, 256)
  const int* sy = (const int*)d_in[3];      // (8192,)
  float* out = (float*)d_out;               // (32, 1000)

  char* p = (char*)d_ws;
  float* xq = (float*)p;            p += (size_t)BATCH * PROJ_DIM * 4;
  unsigned* rowmaxU = (unsigned*)p; p += 128;
  float* sxp = (float*)p;           p += (size_t)NUM_SUPPORT * PROJ_DIM * 4;
  float* sc = (float*)p;            p += (size_t)BATCH * NUM_SUPPORT * 4;
  unsigned short* A2 = (unsigned short*)p; p += (size_t)NUM_SUPPORT * ACOLS * 2;
  unsigned short* WT = (unsigned short*)p; // 256*3072*2

  prep_w_kernel<<<dim3(1024), dim3(256), 0, stream>>>(W, WT);
  prep_a_kernel<<<dim3(NUM_SUPPORT), dim3(256), 0, stream>>>(sx, A2);
  proj_x_kernel<<<dim3(BATCH, 8), dim3(256), 0, stream>>>(x, W, xq, rowmaxU);
  sxp_mfma_kernel<<<dim3(NUM_SUPPORT / 128, PROJ_DIM / 64), dim3(256), 0,
                    stream>>>(A2, WT, sxp);
  score_kernel<<<dim3(NUM_SUPPORT / 256, BATCH / 4), dim3(256), 0, stream>>>(
      xq, sxp, sc, rowmaxU);
  finish_kernel<<<dim3(BATCH), dim3(1024), 0, stream>>>(sc, rowmaxU, sy, out);
}